// Round 4
// baseline (278.950 us; speedup 1.0000x reference)
//
#include <hip/hip_runtime.h>
#include <math.h>

#define NCL 21
#define CIN 256
#define HW 4096
#define PADK 24
#define NB 2

static __device__ __forceinline__ float fastrcp(float x) {
  return __builtin_amdgcn_rcpf(x);
}

// ---------------------------------------------------------------------------
// Kernel A: f1/f2 = 1x1 conv (w @ feat + b). Block = 16 q x 16 c-chunks of 16
// channels; LDS reduction. Also zero-fills lbuf + corr_out (replaces two
// hipMemsetAsync dispatches; stream order makes them visible to k_stats /
// k_corrout atomics).
#define QT 16
#define CCH 16
__global__ __launch_bounds__(256) void k_feat(
    const float* __restrict__ feat, const float* __restrict__ w1,
    const float* __restrict__ b1, const float* __restrict__ w2,
    const float* __restrict__ b2, float* __restrict__ f1T,
    float* __restrict__ f2, float* __restrict__ lbuf,
    float* __restrict__ corr_out) {
  const int t = threadIdx.x;
  const int bid = blockIdx.y * (HW / QT) + blockIdx.x;  // 0..511
  // zero-fill: corr_out = 43008 float4 (84/block), lbuf = 8192 f (16/block)
  {
    float4* co4 = (float4*)corr_out;
    const int base = bid * 84;
    for (int o = t; o < 84; o += 256) co4[base + o] = make_float4(0, 0, 0, 0);
    if (t < 16) lbuf[bid * 16 + t] = 0.f;
  }
  const int qi = t & 15, ch = t >> 4;
  const int n = blockIdx.y;
  const int q = blockIdx.x * QT + qi;
  const int c0 = ch * CCH;
  const float* fp = feat + ((size_t)n * CIN + c0) * HW + q;
  float a1[NCL], a2[NCL];
#pragma unroll
  for (int k = 0; k < NCL; ++k) { a1[k] = 0.f; a2[k] = 0.f; }
#pragma unroll
  for (int cc = 0; cc < CCH; ++cc) {
    float v = fp[(size_t)cc * HW];
#pragma unroll
    for (int k = 0; k < NCL; ++k) {
      a1[k] = fmaf(v, w1[k * CIN + c0 + cc], a1[k]);
      a2[k] = fmaf(v, w2[k * CIN + c0 + cc], a2[k]);
    }
  }
  __shared__ float p1[CCH][QT][NCL];
  __shared__ float p2[CCH][QT][NCL];
#pragma unroll
  for (int k = 0; k < NCL; ++k) { p1[ch][qi][k] = a1[k]; p2[ch][qi][k] = a2[k]; }
  __syncthreads();
  for (int o = t; o < QT * NCL; o += 256) {
    int qq = o & 15, k = o >> 4;
    float s1 = b1[k], s2 = b2[k];
#pragma unroll
    for (int c = 0; c < CCH; ++c) { s1 += p1[c][qq][k]; s2 += p2[c][qq][k]; }
    int qg = blockIdx.x * QT + qq;
    f1T[((size_t)n * HW + qg) * PADK + k] = s1;
    f2[((size_t)n * NCL + k) * HW + qg] = s2;
  }
}

// ---------------------------------------------------------------------------
// Kernel B: out_temp = bilinear downsample of out (128x128 -> 64x64, align
// corners). Stored transposed+padded [n][p][24].
__global__ __launch_bounds__(256) void k_outr(
    const float* __restrict__ out, float* __restrict__ otT) {
  int idx = blockIdx.x * 256 + threadIdx.x;
  if (idx >= NB * NCL * HW) return;
  int p = idx & (HW - 1);
  int nk = idx >> 12;
  int i = p >> 6, j = p & 63;
  double sy = (double)i * (127.0 / 63.0);
  double sx = (double)j * (127.0 / 63.0);
  int y0 = (int)sy, x0 = (int)sx;
  float wy = (float)(sy - y0), wx = (float)(sx - x0);
  int y1 = min(y0 + 1, 127), x1 = min(x0 + 1, 127);
  const float* src = out + (size_t)nk * (128 * 128);
  float v00 = src[y0 * 128 + x0], v10 = src[y1 * 128 + x0];
  float v01 = src[y0 * 128 + x1], v11 = src[y1 * 128 + x1];
  float r0 = v00 * (1.f - wy) + v10 * wy;
  float r1 = v01 * (1.f - wy) + v11 * wy;
  float val = r0 * (1.f - wx) + r1 * wx;
  int n = nk / NCL, c = nk % NCL;
  otT[((size_t)n * HW + p) * PADK + c] = val;
}

// ---------------------------------------------------------------------------
// Kernel C: l[n][p] += sum_q exp(S[n][p][q]) over a q-quarter. f1 tile staged
// in LDS (broadcast ds_read replaces the K$-saturating s_load stream).
#define PT 16
__global__ __launch_bounds__(256) void k_stats(
    const float* __restrict__ f1T, const float* __restrict__ f2,
    float* __restrict__ l) {
  __shared__ float sf1[PT * PADK];  // 384 floats
  const int t = threadIdx.x;
  const int n = blockIdx.z;
  const int pbase = blockIdx.x * PT;
  const int q0 = blockIdx.y * 1024 + t * 4;
  if (t < 96)
    ((float4*)sf1)[t] =
        ((const float4*)(f1T + ((size_t)n * HW + pbase) * PADK))[t];
  __syncthreads();
  const float* f2n = f2 + (size_t)n * NCL * HW;
  const float SCALE = 1.0f / sqrtf(21.0f);
  float4 fq[NCL];
#pragma unroll
  for (int k = 0; k < NCL; ++k)
    fq[k] = *(const float4*)(f2n + (size_t)k * HW + q0);
  float sums[PT];
#pragma unroll
  for (int p = 0; p < PT; ++p) {
    const float* f1p = sf1 + p * PADK;  // LDS broadcast
    float s0 = 0.f, s1 = 0.f, s2 = 0.f, s3 = 0.f;
#pragma unroll
    for (int k = 0; k < NCL; ++k) {
      float a = f1p[k];
      s0 = fmaf(a, fq[k].x, s0);
      s1 = fmaf(a, fq[k].y, s1);
      s2 = fmaf(a, fq[k].z, s2);
      s3 = fmaf(a, fq[k].w, s3);
    }
    sums[p] = __expf(s0 * SCALE) + __expf(s1 * SCALE) + __expf(s2 * SCALE) +
              __expf(s3 * SCALE);
  }
  __shared__ float part[4][PT];
  const int wave = t >> 6, lane = t & 63;
#pragma unroll
  for (int p = 0; p < PT; ++p) {
    float s = sums[p];
    for (int off = 32; off > 0; off >>= 1) s += __shfl_xor(s, off, 64);
    if (lane == 0) part[wave][p] = s;
  }
  __syncthreads();
  if (t < PT) {
    float tot = part[0][t] + part[1][t] + part[2][t] + part[3][t];
    atomicAdd(l + (size_t)n * HW + pbase + t, tot);
  }
}

// ---------------------------------------------------------------------------
// Kernel D: corr_out[n][c][q] += sum_p otT[n][p][c] * exp(S[p][q]) / l[p].
// p tile (f1, ot, rcp(l)) staged in LDS once per block; p-loop reads are
// same-address broadcasts. 2 q/thread for ILP. Grid 8 x 64 x 2 = 1024 blocks.
#define DPS 64
__global__ __launch_bounds__(256) void k_corrout(
    const float* __restrict__ f1T, const float* __restrict__ f2,
    const float* __restrict__ otT, const float* __restrict__ l,
    float* __restrict__ corr_out) {
  __shared__ float sf1[DPS * PADK];  // 1536 floats
  __shared__ float sot[DPS * PADK];
  __shared__ float sil[DPS];
  const int t = threadIdx.x;
  const int n = blockIdx.z;
  const int q = blockIdx.x * 512 + t * 2;
  const int pbase = blockIdx.y * DPS;
  const float4* gf1 = (const float4*)(f1T + ((size_t)n * HW + pbase) * PADK);
  const float4* got = (const float4*)(otT + ((size_t)n * HW + pbase) * PADK);
  for (int o = t; o < 384; o += 256) {
    ((float4*)sf1)[o] = gf1[o];
    ((float4*)sot)[o] = got[o];
  }
  if (t < DPS) sil[t] = fastrcp(l[(size_t)n * HW + pbase + t]);
  __syncthreads();
  const float* f2n = f2 + (size_t)n * NCL * HW;
  const float SCALE = 1.0f / sqrtf(21.0f);
  float2 fq[NCL];
#pragma unroll
  for (int k = 0; k < NCL; ++k)
    fq[k] = *(const float2*)(f2n + (size_t)k * HW + q);
  float2 acc[NCL];
#pragma unroll
  for (int k = 0; k < NCL; ++k) acc[k] = make_float2(0.f, 0.f);
  for (int p = 0; p < DPS; ++p) {
    const float* f1p = sf1 + p * PADK;
    const float* otp = sot + p * PADK;
    float sa = 0.f, sb = 0.f, ta = 0.f, tb = 0.f;  // 2 chains x 2 q
#pragma unroll
    for (int k = 0; k < 11; ++k) {
      float a = f1p[k];
      sa = fmaf(a, fq[k].x, sa);
      ta = fmaf(a, fq[k].y, ta);
    }
#pragma unroll
    for (int k = 11; k < NCL; ++k) {
      float a = f1p[k];
      sb = fmaf(a, fq[k].x, sb);
      tb = fmaf(a, fq[k].y, tb);
    }
    float il = sil[p];
    float w0 = __expf((sa + sb) * SCALE) * il;
    float w1 = __expf((ta + tb) * SCALE) * il;
#pragma unroll
    for (int c = 0; c < NCL; ++c) {
      float o = otp[c];
      acc[c].x = fmaf(o, w0, acc[c].x);
      acc[c].y = fmaf(o, w1, acc[c].y);
    }
  }
  float* co = corr_out + (size_t)n * NCL * HW + q;
#pragma unroll
  for (int c = 0; c < NCL; ++c) {
    atomicAdd(co + (size_t)c * HW, acc[c].x);
    atomicAdd(co + (size_t)c * HW + 1, acc[c].y);
  }
}

// ---------------------------------------------------------------------------
// Kernel E1: unnormalized sampled rows (min/max norm is scale-invariant, so
// the softmax denominator is skipped). Rows parked in the output-0 slots.
__global__ __launch_bounds__(256) void k_rows(
    const float* __restrict__ f1T, const float* __restrict__ f2,
    const int* __restrict__ index, float* __restrict__ out0) {
  const int t = threadIdx.x;
  const int qc = blockIdx.x;  // 0..3
  const int i = blockIdx.y;
  const int n = blockIdx.z;
  int p = index[i];
  p = max(0, min(p, HW - 1));
  const float* f1p = f1T + ((size_t)n * HW + p) * PADK;  // uniform
  const float* f2n = f2 + (size_t)n * NCL * HW;
  const float SCALE = 1.0f / sqrtf(21.0f);
  const int q0 = qc * 1024 + t * 4;
  float4 fq[NCL];
#pragma unroll
  for (int k = 0; k < NCL; ++k)
    fq[k] = *(const float4*)(f2n + (size_t)k * HW + q0);
  float s0 = 0.f, s1 = 0.f, s2 = 0.f, s3 = 0.f;
#pragma unroll
  for (int k = 0; k < NCL; ++k) {
    float a = f1p[k];
    s0 = fmaf(a, fq[k].x, s0);
    s1 = fmaf(a, fq[k].y, s1);
    s2 = fmaf(a, fq[k].z, s2);
    s3 = fmaf(a, fq[k].w, s3);
  }
  float4 r = make_float4(__expf(s0 * SCALE), __expf(s1 * SCALE),
                         __expf(s2 * SCALE), __expf(s3 * SCALE));
  *(float4*)(out0 + ((size_t)n * 128 + i) * (128 * 128) + q0) = r;
}

// ---------------------------------------------------------------------------
// Kernel E2: row -> bilinear 64->128 (in-kernel table) -> min/max norm ->
// >0.5 booleans as 1.0/0.0 (overwrites slot).
__global__ __launch_bounds__(256) void k_norm(float* __restrict__ out0) {
  __shared__ float row[HW];
  __shared__ float redmn[4], redmx[4];
  __shared__ float wt[128];
  __shared__ int it[128];
  const int t = threadIdx.x;
  const int i = blockIdx.x;
  const int n = blockIdx.y;
  if (t < 128) {
    double s = (double)t * (63.0 / 127.0);
    int i0 = (int)s;
    wt[t] = (float)(s - i0);
    it[t] = i0;
  }
  float* slot = out0 + ((size_t)n * 128 + i) * (128 * 128);
#pragma unroll
  for (int j = 0; j < 4; ++j)
    *(float4*)(row + t * 4 + j * 1024) =
        *(const float4*)(slot + t * 4 + j * 1024);
  __syncthreads();
  float vv[64];
  float lmn = 1e30f, lmx = -1e30f;
  for (int j = 0; j < 64; ++j) {
    int pix = t + j * 256;
    int yy = pix >> 7, xx = pix & 127;
    int y0 = it[yy], x0 = it[xx];
    float wy = wt[yy], wx = wt[xx];
    int y1 = min(y0 + 1, 63), x1 = min(x0 + 1, 63);
    float r0 = row[y0 * 64 + x0] * (1.f - wy) + row[y1 * 64 + x0] * wy;
    float r1 = row[y0 * 64 + x1] * (1.f - wy) + row[y1 * 64 + x1] * wy;
    float v = r0 * (1.f - wx) + r1 * wx;
    vv[j] = v;
    lmn = fminf(lmn, v);
    lmx = fmaxf(lmx, v);
  }
  for (int off = 32; off > 0; off >>= 1) {
    lmn = fminf(lmn, __shfl_xor(lmn, off, 64));
    lmx = fmaxf(lmx, __shfl_xor(lmx, off, 64));
  }
  const int wave = t >> 6, lane = t & 63;
  if (lane == 0) { redmn[wave] = lmn; redmx[wave] = lmx; }
  __syncthreads();
  float mn = fminf(fminf(redmn[0], redmn[1]), fminf(redmn[2], redmn[3]));
  float mx = fmaxf(fmaxf(redmx[0], redmx[1]), fmaxf(redmx[2], redmx[3]));
  float rng = mx - mn;
  for (int j = 0; j < 64; ++j) {
    int pix = t + j * 256;
    float nrm = (vv[j] - mn) / rng;
    slot[pix] = (nrm > 0.5f) ? 1.0f : 0.0f;
  }
}

// ---------------------------------------------------------------------------
extern "C" void kernel_launch(void* const* d_in, const int* in_sizes, int n_in,
                              void* d_out, int out_size, void* d_ws,
                              size_t ws_size, hipStream_t stream) {
  (void)in_sizes; (void)n_in; (void)out_size; (void)ws_size;
  const float* feat = (const float*)d_in[0];
  const float* out  = (const float*)d_in[1];
  const float* w1   = (const float*)d_in[2];
  const float* b1   = (const float*)d_in[3];
  const float* w2   = (const float*)d_in[4];
  const float* b2   = (const float*)d_in[5];
  const int* index  = (const int*)d_in[6];

  float* ws   = (float*)d_ws;
  float* f1T  = ws;                                   // 2*4096*24 = 196608
  float* f2   = ws + 196608;                          // 2*21*4096 = 172032
  float* otT  = ws + 196608 + 172032;                 // 196608
  float* lbuf = ws + 196608 + 172032 + 196608;        // 8192

  float* out0     = (float*)d_out;                    // 2*128*128*128
  float* corr_out = out0 + (size_t)NB * 128 * 128 * 128;  // 2*21*4096

  k_feat<<<dim3(HW / QT, 2), 256, 0, stream>>>(feat, w1, b1, w2, b2, f1T, f2,
                                               lbuf, corr_out);
  k_outr<<<dim3(672), 256, 0, stream>>>(out, otT);
  k_stats<<<dim3(HW / PT, 4, 2), 256, 0, stream>>>(f1T, f2, lbuf);
  k_rows<<<dim3(4, 128, 2), 256, 0, stream>>>(f1T, f2, index, out0);
  k_corrout<<<dim3(8, HW / DPS, 2), 256, 0, stream>>>(f1T, f2, otT, lbuf,
                                                      corr_out);
  k_norm<<<dim3(128, 2), 256, 0, stream>>>(out0);
}